// Round 18
// baseline (361.026 us; speedup 1.0000x reference)
//
#include <hip/hip_runtime.h>
#include <hip/hip_bf16.h>

#define B_    16
#define C_    96
#define H_    224
#define W_    224
#define COUT_ 96
#define GH_   14
#define GW_   14
#define P_    196          // GH_*GW_
#define HW_   (H_*W_)      // 50176
#define NCH_  12           // 8-channel chunks

#define AS1 __attribute__((address_space(1)))
#define AS3 __attribute__((address_space(3)))

typedef __attribute__((ext_vector_type(8))) unsigned short ushort8;
typedef __attribute__((ext_vector_type(8))) short        short8;   // MFMA bf16x8 operand
typedef __attribute__((ext_vector_type(4))) float        f32x4;

__device__ __forceinline__ unsigned short f2bf(float f) {
    union { __hip_bfloat16 h; unsigned short u; } cv;
    cv.h = __float2bfloat16(f);
    return cv.u;
}

// ---------------------------------------------------------------------------
// Kernel 0: of (COUT,C,3,3) f32 -> ofb3 in MFMA-FRAGMENT ORDER:
//   ofb3[tap][cs][ni][lane][8ch],  lane = mrow + 16*kgrp,
//   cout = ni*16 + (lane&15), c = cs*32 + (lane>>4)*8 + j.
// Wave bf load = base + lane*16B: coalesced 1 KB, same across waves.
// ---------------------------------------------------------------------------
__global__ __launch_bounds__(256) void prep_ofb(const float* __restrict__ of,
                                                unsigned short* __restrict__ ofb3,
                                                unsigned short* __restrict__ zp) {
    if (blockIdx.x == 0 && threadIdx.x < 128) zp[threadIdx.x] = 0;
    int e = blockIdx.x * 256 + threadIdx.x;        // 9*3*6*64*8 = 82944
    if (e < 82944) {
        int j    = e & 7;
        int l    = (e >> 3) & 63;
        int ni   = (e >> 9) % 6;
        int cs   = (e / 3072) % 3;
        int tap  = e / 9216;
        int cout = ni * 16 + (l & 15);
        int c    = cs * 32 + (l >> 4) * 8 + j;
        ofb3[e] = f2bf(of[((size_t)cout * 96 + c) * 9 + tap]);
    }
}

// ---------------------------------------------------------------------------
// Kernel 1: per-patch depthwise 3x3 (patch-local zero padding).
// x: (B,C,H,W) f32 -> sa: (B, 12, H, W, 8) bf16  (8-ch chunk planes).
// (R5-proven: ~107 us, near traffic floor. Unchanged.)
// ---------------------------------------------------------------------------
__global__ __launch_bounds__(256) void sa_kernel(const float* __restrict__ x,
                                                 const float* __restrict__ pf,
                                                 unsigned short* __restrict__ sa) {
    int bid   = blockIdx.x;
    int patch = bid % P_;
    int b     = bid / P_;
    int gh = patch / GW_, gw = patch % GW_;
    int t  = threadIdx.x;
    int py = t >> 4, px = t & 15;
    int y  = gh * 16 + py, xx = gw * 16 + px;

    __shared__ float xs[2][8][256];    // 16 KB double-buffered x slice

    const float* xp0 = x + (size_t)b * C_ * HW_ + (size_t)y * W_ + xx;

    float lf[8];
    #pragma unroll
    for (int ch = 0; ch < 8; ++ch) lf[ch] = xp0[(size_t)ch * HW_];

    for (int cc = 0; cc < NCH_; ++cc) {
        int buf = cc & 1;
        #pragma unroll
        for (int ch = 0; ch < 8; ++ch) xs[buf][ch][t] = lf[ch];
        __syncthreads();
        if (cc < NCH_ - 1) {
            #pragma unroll
            for (int ch = 0; ch < 8; ++ch)
                lf[ch] = xp0[(size_t)((cc + 1) * 8 + ch) * HW_];
        }

        ushort8 v;
        #pragma unroll
        for (int ch = 0; ch < 8; ++ch) {
            const float* wgt = pf + ((size_t)(cc * 8 + ch) * P_ + patch) * 9;  // uniform -> s_load
            float a = 0.f;
            #pragma unroll
            for (int dy = -1; dy <= 1; ++dy) {
                int yy = py + dy;
                if ((unsigned)yy < 16u) {
                    #pragma unroll
                    for (int dx = -1; dx <= 1; ++dx) {
                        int xq = px + dx;
                        if ((unsigned)xq < 16u)
                            a = fmaf(xs[buf][ch][yy * 16 + xq],
                                     wgt[(dy + 1) * 3 + (dx + 1)], a);
                    }
                }
            }
            v[ch] = f2bf(a);
        }
        *(ushort8*)&sa[(((size_t)(b * NCH_ + cc) * H_ + y) * W_ + xx) * 8] = v;
    }
}

// ---------------------------------------------------------------------------
// Kernel 2: implicit-GEMM MFMA conv + exact GELU, full-patch blocks.
// R18 = R17 + two levers:
//   (a) bf pipeline DEPTH 2 (ring bf0/bf1/bf2, compile-time T%3 naming):
//       at step T, step T+2's 6 loads are issued; the wait before step
//       T+1's burst is a counted vmcnt(12->6), ~300-420 cyc of cover vs
//       ~200-300 cyc L1/L2 latency (R17's depth 1 was ~100 cyc short);
//   (b) s_setprio(1) around the MFMA burst (T5): after the prologue
//       barrier the 4 waves run barrier-free and drift out of phase ->
//       scheduler favors MFMA-entering waves over load-issuing ones.
// Everything else identical to R17 (fragment-order ofb3, 13-pitch A tile,
// stage-once DMA, one barrier, acc[4][6], 4 all-M waves, (256,2)).
// ---------------------------------------------------------------------------
__global__ __launch_bounds__(256, 2) void conv2_mfma(const unsigned short* __restrict__ sa,
                                                     const unsigned short* __restrict__ ofb3,
                                                     const unsigned short* __restrict__ zp,
                                                     float* __restrict__ out) {
    // XCD-aware swizzle (3136 % 8 == 0 -> bijective)
    int bid0 = blockIdx.x;
    int bid  = (bid0 % 8) * (3136 / 8) + bid0 / 8;
    int patch = bid % P_;
    int b     = bid / P_;
    int gh = patch / GW_, gw = patch % GW_;
    int y0 = gh * 16, x0 = gw * 16;

    int t = threadIdx.x;
    int w = t >> 6, l = t & 63;             // 4 all-M waves
    int mrow = l & 15, kgrp = l >> 4;

    __shared__ ushort8 at8[4352];           // 18*18 px x 13 slots (+140 trash) = 69632 B

    // ---- single staging burst: 18x18 halo, px-major, 13-slot pitch ----
    #pragma unroll
    for (int i = 0; i < 17; ++i) {
        int v = t + i * 256;                // 0..4351; [0,4212) real
        const unsigned short* src = zp;
        if (v < 4212) {
            int hpx = v / 13, ccl = v - hpx * 13;   // slot 12 = bank pad (zp)
            if (ccl < 12) {
                int gy = y0 - 1 + hpx / 18, gx = x0 - 1 + hpx % 18;
                if ((unsigned)gy < (unsigned)H_ && (unsigned)gx < (unsigned)W_)
                    src = &sa[(((size_t)(b * NCH_ + ccl) * H_ + gy) * W_ + gx) * 8];
            }
        }
        __builtin_amdgcn_global_load_lds((const AS1 unsigned int*)src,
                                         (AS3 unsigned int*)&at8[v], 16, 0, 0);
    }

    f32x4 acc[4][6];
    #pragma unroll
    for (int mi = 0; mi < 4; ++mi)
        #pragma unroll
        for (int ni = 0; ni < 6; ++ni)
            acc[mi][ni] = (f32x4)0.f;

    __syncthreads();                        // drain DMA; tile visible; queue EMPTY

    const unsigned short* at = (const unsigned short*)at8;  // [px][13 slots][8ch]

    // bf fetch for step T (tap = T/3, cs = T%3), fragment-order: +lane*16B
    short8 bf0[6], bf1[6], bf2[6];
    auto LOADBF = [&](short8* dst, int T) {
        const unsigned short* p = ofb3 + (size_t)(T / 3) * 9216 + (T % 3) * 3072 + l * 8;
        #pragma unroll
        for (int ni = 0; ni < 6; ++ni)
            dst[ni] = *(const short8*)&p[ni * 512];
    };

    LOADBF(bf0, 0);
    LOADBF(bf1, 1);
    #pragma unroll                          // full unroll: ring index static
    for (int T = 0; T < 27; ++T) {
        short8* cur = (T % 3 == 0) ? bf0 : (T % 3 == 1) ? bf1 : bf2;
        short8* pre = (T % 3 == 0) ? bf2 : (T % 3 == 1) ? bf0 : bf1;
        if (T + 2 < 27) LOADBF(pre, T + 2); // issue 2 steps ahead (T4 depth-2)
        __builtin_amdgcn_sched_barrier(0);  // pin loads above the MFMA burst

        int tap = T / 3, cs = T % 3;
        int ky = tap / 3, kx = tap % 3;
        __builtin_amdgcn_s_setprio(1);      // favor MFMA-entering wave (T5)
        #pragma unroll
        for (int mi = 0; mi < 4; ++mi) {
            short8 af = *(const short8*)&at[((w * 4 + mi + ky) * 18 + kx + mrow) * 104
                                            + (cs * 4 + kgrp) * 8];
            #pragma unroll
            for (int ni = 0; ni < 6; ++ni)
                acc[mi][ni] = __builtin_amdgcn_mfma_f32_16x16x32_bf16(
                    af, cur[ni], acc[mi][ni], 0, 0, 0);
        }
        __builtin_amdgcn_s_setprio(0);
    }

    // ---- epilogue: exact GELU + f32x4 stores ----
    #pragma unroll
    for (int mi = 0; mi < 4; ++mi) {
        int gy = y0 + w * 4 + mi;
        #pragma unroll
        for (int ni = 0; ni < 6; ++ni) {
            int cout = ni * 16 + mrow;
            f32x4 gv;
            #pragma unroll
            for (int j = 0; j < 4; ++j) {
                float vv = acc[mi][ni][j];
                gv[j] = 0.5f * vv * (1.0f + erff(vv * 0.70710678118f));
            }
            *(f32x4*)&out[((size_t)b * COUT_ + cout) * HW_ + (size_t)gy * W_ +
                          x0 + kgrp * 4] = gv;
        }
    }
}

extern "C" void kernel_launch(void* const* d_in, const int* in_sizes, int n_in,
                              void* d_out, int out_size, void* d_ws, size_t ws_size,
                              hipStream_t stream) {
    const float* x  = (const float*)d_in[0];
    const float* pf = (const float*)d_in[1];
    const float* of = (const float*)d_in[2];
    float* out = (float*)d_out;

    unsigned short* sa   = (unsigned short*)d_ws;                       // 154,140,672 B
    unsigned short* ofb3 = (unsigned short*)((char*)d_ws + 154140672);  // + 165,888 B
    unsigned short* zp   = (unsigned short*)((char*)d_ws + 154306560);  // + 256 B zero-page

    prep_ofb<<<324, 256, 0, stream>>>(of, ofb3, zp);
    sa_kernel<<<B_ * P_, 256, 0, stream>>>(x, pf, sa);
    conv2_mfma<<<B_ * P_, 256, 0, stream>>>(sa, ofb3, zp, out);
}